// Round 1
// baseline (106.777 us; speedup 1.0000x reference)
//
#include <hip/hip_runtime.h>

// SimpleGCNConv: out = rownorm(setadj(edge_index) + I) @ x @ W^T + b
// N=8192, E=262144, D=128, fp32. Dedup via dense bitmap (8 MB in d_ws);
// duplicate edges count ONCE (.set), self-loop added ON TOP (so a self-edge
// bit + eye correctly yields 2/deg, matching the reference).
//
// R5: M=8 nodes/block (256 thr), halving block count (W re-read 128->64 MB).
// Phase B bounds each wave-pair by its own 4-node max and guards each node
// by its padded count (wave-uniform guards: counts are padded to x4 and k
// spreads <4 within a wave) -> ~20% fewer gather loads vs global-Lmax pad.
// edge_scatter reads 4 edges/thread via int4.

typedef unsigned int uint32;

#define NNODES 8192
#define DF 128
#define WPR 256        // bitmap words per row
#define M 8            // nodes per block
#define CAP 192        // neighbor list cap (deg ~ Poisson(32); max row ~70)

__global__ void edge_scatter(const int* __restrict__ ei, int E,
                             uint32* __restrict__ bm) {
    int e4 = blockIdx.x * blockDim.x + threadIdx.x;
    int E4 = E >> 2;
    if (e4 < E4) {
        const int4* s4 = (const int4*)ei;
        const int4* d4 = (const int4*)(ei + E);
        int4 s = s4[e4], d = d4[e4];
        atomicOr(&bm[(size_t)s.x * WPR + (d.x >> 5)], 1u << (d.x & 31));
        atomicOr(&bm[(size_t)s.y * WPR + (d.y >> 5)], 1u << (d.y & 31));
        atomicOr(&bm[(size_t)s.z * WPR + (d.z >> 5)], 1u << (d.z & 31));
        atomicOr(&bm[(size_t)s.w * WPR + (d.w >> 5)], 1u << (d.w & 31));
    }
    if (e4 == 0) {                        // tail (E%4 != 0) — none for E=262144
        for (int e = E & ~3; e < E; ++e) {
            int src = ei[e], dst = ei[E + e];
            atomicOr(&bm[(size_t)src * WPR + (dst >> 5)], 1u << (dst & 31));
        }
    }
}

__global__ __launch_bounds__(256) void gcn_fused(
    const float* __restrict__ x,
    const uint32* __restrict__ bm,
    const float4* __restrict__ zrow,   // 128 zero floats (in d_ws, memset)
    const float* __restrict__ W,
    const float* __restrict__ b,
    float* __restrict__ out)
{
    __shared__ int nbr[M][CAP];                     // 6 KB
    __shared__ int cnt_s[M];
    __shared__ __align__(16) float part[M][4][DF];  // 16 KB
    __shared__ float agg[M][DF];                    // 4 KB

    const int t    = threadIdx.x;
    const int lane = t & 63;
    const int wv   = t >> 6;          // 0..3
    const int node0 = blockIdx.x * M;

    // ---- Phase A: one wave per bitmap row (2 passes); prefix-sum, no atomics.
    #pragma unroll
    for (int pass = 0; pass < 2; ++pass) {
        const int m = pass * 4 + wv;
        const uint4* r = (const uint4*)(bm + (size_t)(node0 + m) * WPR);
        uint4 w = r[lane];                           // 16 B/lane, coalesced
        int c = __popc(w.x) + __popc(w.y) + __popc(w.z) + __popc(w.w);
        int v = c;                                   // inclusive wave scan
        #pragma unroll
        for (int dd = 1; dd < 64; dd <<= 1) {
            int up = __shfl_up(v, dd);
            if (lane >= dd) v += up;
        }
        int off = v - c;                             // exclusive prefix
        if (lane == 63) cnt_s[m] = v;
        uint32 ws[4] = {w.x, w.y, w.z, w.w};
        #pragma unroll
        for (int q = 0; q < 4; ++q) {
            uint32 word = ws[q];
            int base = (4 * lane + q) << 5;
            while (word) {
                int bit = __ffs(word) - 1; word &= word - 1;
                if (off < CAP) nbr[m][off] = base + bit;
                off++;
            }
        }
    }
    __syncthreads();

    int cnt[M];
    int allmax = 0;
    #pragma unroll
    for (int m = 0; m < M; ++m) { cnt[m] = cnt_s[m]; allmax = max(allmax, cnt[m]); }
    const bool overflow = (allmax > CAP);            // statistically never

    // Pad each node's list to its own multiple-of-4 with -1 (<=3 slots).
    if (t < M) {
        int cm = min(cnt_s[t], CAP);
        int c4 = (cm + 3) & ~3;
        for (int k = cm; k < c4; ++k) nbr[t][k] = -1;
    }
    __syncthreads();

    const int half = t >> 7;          // 0: nodes 0-3, 1: nodes 4-7
    const int d    = t & 127;

    if (!overflow) {
        // ---- Phase B: float4 gather. Wave-pair `half` owns 4 nodes; group g
        // handles k===g (mod 4); 4 chains interleaved -> 4 loads in flight.
        const int g = (t >> 5) & 3;   // 0..3
        const int c = t & 31;         // float4 chunk within row
        const float4* x4 = (const float4*)x;

        int c4v[4];
        int Lwp = 0;
        #pragma unroll
        for (int i = 0; i < 4; ++i) {
            int cm = min(cnt[4 * half + i], CAP);
            c4v[i] = (cm + 3) & ~3;
            Lwp = max(Lwp, c4v[i]);
        }

        float4 acc[4];
        #pragma unroll
        for (int i = 0; i < 4; ++i) acc[i] = make_float4(0.f, 0.f, 0.f, 0.f);

        for (int k = g; k < Lwp; k += 4) {
            #pragma unroll
            for (int i = 0; i < 4; ++i) {
                if (k < c4v[i]) {     // wave-uniform (c4v multiple of 4)
                    int j = nbr[4 * half + i][k];
                    const float4* p = (j >= 0) ? (x4 + (size_t)j * (DF / 4) + c)
                                               : (zrow + c);
                    float4 vx = *p;
                    acc[i].x += vx.x; acc[i].y += vx.y;
                    acc[i].z += vx.z; acc[i].w += vx.w;
                }
            }
        }

        #pragma unroll
        for (int i = 0; i < 4; ++i)
            *(float4*)&part[4 * half + i][g][c * 4] = acc[i];
        __syncthreads();

        // Reduce groups, add eye, normalize.
        #pragma unroll
        for (int i = 0; i < 4; ++i) {
            int m = 4 * half + i;
            float s = part[m][0][d] + part[m][1][d]
                    + part[m][2][d] + part[m][3][d];
            s += x[(size_t)(node0 + m) * DF + d];    // self-loop on top
            agg[m][d] = s / (float)(1 + cnt[m]);
        }
    } else {
        // Fallback (correctness-safe, never expected): uniform bitmap rescan.
        for (int i = 0; i < 4; ++i) {
            int m = 4 * half + i;
            const uint32* r = bm + (size_t)(node0 + m) * WPR;
            float acc = x[(size_t)(node0 + m) * DF + d];
            for (int w = 0; w < WPR; ++w) {
                uint32 word = r[w];
                int base = w << 5;
                while (word) {
                    int bit = __ffs(word) - 1; word &= word - 1;
                    acc += x[(size_t)(base + bit) * DF + d];
                }
            }
            agg[m][d] = acc / (float)(1 + cnt[m]);
        }
    }
    __syncthreads();

    // ---- Phase C: fused linear. Thread owns out dim d for its half's 4 nodes.
    const float4* Wrow = (const float4*)(W + (size_t)d * DF);
    float bias = b[d];
    float sum[4];
    #pragma unroll
    for (int i = 0; i < 4; ++i) sum[i] = bias;

    #pragma unroll 8
    for (int c4i = 0; c4i < DF / 4; ++c4i) {
        float4 wvv = Wrow[c4i];
        #pragma unroll
        for (int i = 0; i < 4; ++i) {
            const float* a = &agg[4 * half + i][c4i * 4];   // LDS broadcast
            sum[i] += wvv.x * a[0] + wvv.y * a[1]
                    + wvv.z * a[2] + wvv.w * a[3];
        }
    }
    #pragma unroll
    for (int i = 0; i < 4; ++i)
        out[(size_t)(node0 + 4 * half + i) * DF + d] = sum[i];
}

extern "C" void kernel_launch(void* const* d_in, const int* in_sizes, int n_in,
                              void* d_out, int out_size, void* d_ws, size_t ws_size,
                              hipStream_t stream) {
    const float* x = (const float*)d_in[0];
    const int*  ei = (const int*)d_in[1];
    const float* W = (const float*)d_in[2];
    const float* b = (const float*)d_in[3];
    float* out = (float*)d_out;

    uint32* bm = (uint32*)d_ws;
    const size_t bm_bytes = (size_t)NNODES * WPR * sizeof(uint32);   // 8 MB
    const float4* zrow = (const float4*)((char*)d_ws + bm_bytes);    // 512 B zeros
    const int E = in_sizes[1] / 2;

    // d_ws is re-poisoned before every launch: zero bitmap + zero-row.
    hipMemsetAsync(d_ws, 0, bm_bytes + DF * sizeof(float), stream);

    int E4 = E >> 2;
    edge_scatter<<<dim3((E4 + 255) / 256), dim3(256), 0, stream>>>(ei, E, bm);
    gcn_fused<<<dim3(NNODES / M), dim3(256), 0, stream>>>(x, bm, zrow, W, b, out);
}

// Round 3
// 102.951 us; speedup vs baseline: 1.0372x; 1.0372x over previous
//
#include <hip/hip_runtime.h>

// SimpleGCNConv: out = rownorm(setadj(edge_index) + I) @ x @ W^T + b
// N=8192, E=262144, D=128, fp32. Duplicate edges count ONCE (.set),
// self-loop added ON TOP.
//
// R7: dense 8MB bitmap replaced by fixed-capacity per-src buckets
// (cnt[8192] + bkt[8192][CAP], ~6 MB ws, only 33 KB memset) with dedup
// done in LDS (1 KB bitmap/node, atomicOr test-and-set -> append).
// Kernel 1 also streams x once (keep-alive) to re-warm L2/L3 after the
// harness's 256 MiB poison fill, overlapped with the scatter atomics.
// Phase B/C identical to the proven R4 structure (M=4, 128 thr).

typedef unsigned int uint32;

#define NNODES 8192
#define DF 128
#define M 4            // nodes per block
#define CAP 192        // bucket capacity (deg ~ Poisson(32); max row ~70)
#define NTHR 128
#define WPN 256        // LDS bitmap words per node (8192 bits)

__global__ void bucket_scatter(const int* __restrict__ ei, int E,
                               int* __restrict__ cntg, int* __restrict__ bkt,
                               const float4* __restrict__ x4) {
    int e = blockIdx.x * blockDim.x + threadIdx.x;
    if (e < E) {
        int src = ei[e];        // edge_index[0][e]
        int dst = ei[E + e];    // edge_index[1][e]
        int pos = atomicAdd(&cntg[src], 1);
        if (pos < CAP) bkt[(size_t)src * CAP + pos] = dst;
    }
    // x re-warm: E threads cover exactly N*DF/4 float4s (4 MB) when E=262144.
    if (e < NNODES * DF / 4) {
        float4 px = x4[e];
        asm volatile("" :: "v"(px.x), "v"(px.y), "v"(px.z), "v"(px.w));
    }
}

__global__ __launch_bounds__(128) void gcn_fused(
    const float* __restrict__ x,
    const int* __restrict__ ei, int E,
    const int* __restrict__ cntg,
    const int* __restrict__ bkt,
    const float4* __restrict__ zrow,   // 128 zero floats (in memset region)
    const float* __restrict__ W,
    const float* __restrict__ b,
    float* __restrict__ out)
{
    __shared__ int nbr[M][CAP];                     // 3 KB
    __shared__ uint32 lbm[M][WPN];                  // 4 KB dedup bitmaps
    __shared__ int cnt_s[M];
    __shared__ int ovf_s[M];
    __shared__ __align__(16) float part[M][4][DF];  // 8 KB
    __shared__ float agg[M][DF];                    // 2 KB

    const int t     = threadIdx.x;
    const int node0 = blockIdx.x * M;

    // ---- Phase A: dedup buckets via LDS bitmap test-and-set -> nbr lists.
    for (int i = t; i < M * WPN; i += NTHR) ((uint32*)lbm)[i] = 0;
    if (t < M) { cnt_s[t] = 0; ovf_s[t] = 0; }
    __syncthreads();

    #pragma unroll
    for (int m = 0; m < M; ++m) {
        const int node = node0 + m;
        const int raw = cntg[node];
        if (raw <= CAP) {
            for (int k = t; k < raw; k += NTHR) {
                int dst = bkt[(size_t)node * CAP + k];
                uint32 bit = 1u << (dst & 31);
                uint32 old = atomicOr(&lbm[m][dst >> 5], bit);
                if (!(old & bit)) {
                    int pos = atomicAdd(&cnt_s[m], 1);
                    nbr[m][pos] = dst;              // pos < raw <= CAP
                }
            }
        } else {
            // Overflow (statistically never): bucket dropped edges; rebuild
            // this node's bitmap from the full edge list (bits only).
            if (t == 0) ovf_s[m] = 1;
            for (int e = t; e < E; e += NTHR) {
                if (ei[e] == node) {
                    int dst = ei[E + e];
                    uint32 bit = 1u << (dst & 31);
                    uint32 old = atomicOr(&lbm[m][dst >> 5], bit);
                    if (!(old & bit)) atomicAdd(&cnt_s[m], 1);
                }
            }
        }
    }
    __syncthreads();

    const bool overflow = (ovf_s[0] | ovf_s[1] | ovf_s[2] | ovf_s[3]) != 0;
    const int c0 = cnt_s[0], c1 = cnt_s[1], c2 = cnt_s[2], c3 = cnt_s[3];
    int Lmax = max(max(c0, c1), max(c2, c3));
    int L = (min(Lmax, CAP) + 3) & ~3;               // pad to multiple of 4

    // Pad lists with -1 (sentinel -> zero row).
    for (int m = 0; m < M; ++m) {
        int cm = min(cnt_s[m], CAP);
        for (int k = cm + t; k < L; k += NTHR) nbr[m][k] = -1;
    }
    __syncthreads();

    if (!overflow) {
        // ---- Phase B: float4 gather. group g handles neighbors k===g (mod 4);
        // all M chains interleaved per iteration -> 4 loads in flight/thread.
        const int g = t >> 5;       // 0..3
        const int c = t & 31;       // float4 chunk
        const float4* x4 = (const float4*)x;

        float4 acc[M];
        #pragma unroll
        for (int m = 0; m < M; ++m) acc[m] = make_float4(0.f, 0.f, 0.f, 0.f);

        for (int k = g; k < L; k += 4) {
            #pragma unroll
            for (int m = 0; m < M; ++m) {
                int j = nbr[m][k];
                const float4* p = (j >= 0) ? (x4 + (size_t)j * (DF / 4) + c)
                                           : (zrow + c);
                float4 vx = *p;
                acc[m].x += vx.x; acc[m].y += vx.y;
                acc[m].z += vx.z; acc[m].w += vx.w;
            }
        }

        #pragma unroll
        for (int m = 0; m < M; ++m)
            *(float4*)&part[m][g][c * 4] = acc[m];
        __syncthreads();

        // Reduce groups, add eye, normalize.
        #pragma unroll
        for (int m = 0; m < M; ++m) {
            float s = part[m][0][t] + part[m][1][t]
                    + part[m][2][t] + part[m][3][t];
            s += x[(size_t)(node0 + m) * DF + t];    // self-loop on top
            agg[m][t] = s / (float)(1 + cnt_s[m]);
        }
    } else {
        // Fallback (correctness-safe, never expected): per-dim accumulation
        // straight from the LDS bitmaps (uniform across threads).
        for (int m = 0; m < M; ++m) {
            float acc = x[(size_t)(node0 + m) * DF + t];
            for (int w = 0; w < WPN; ++w) {
                uint32 word = lbm[m][w];
                int base = w << 5;
                while (word) {
                    int bit = __ffs(word) - 1; word &= word - 1;
                    acc += x[(size_t)(base + bit) * DF + t];
                }
            }
            agg[m][t] = acc / (float)(1 + cnt_s[m]);
        }
    }
    __syncthreads();

    // ---- Phase C: fused linear. Thread t owns out dim t for all M nodes.
    const float4* Wrow = (const float4*)(W + (size_t)t * DF);
    float bias = b[t];
    float sum[M];
    #pragma unroll
    for (int m = 0; m < M; ++m) sum[m] = bias;

    #pragma unroll 8
    for (int c4 = 0; c4 < DF / 4; ++c4) {
        float4 wvv = Wrow[c4];
        #pragma unroll
        for (int m = 0; m < M; ++m) {
            sum[m] += wvv.x * agg[m][c4 * 4 + 0] + wvv.y * agg[m][c4 * 4 + 1]
                    + wvv.z * agg[m][c4 * 4 + 2] + wvv.w * agg[m][c4 * 4 + 3];
        }
    }
    #pragma unroll
    for (int m = 0; m < M; ++m)
        out[(size_t)(node0 + m) * DF + t] = sum[m];
}

extern "C" void kernel_launch(void* const* d_in, const int* in_sizes, int n_in,
                              void* d_out, int out_size, void* d_ws, size_t ws_size,
                              hipStream_t stream) {
    const float* x = (const float*)d_in[0];
    const int*  ei = (const int*)d_in[1];
    const float* W = (const float*)d_in[2];
    const float* b = (const float*)d_in[3];
    float* out = (float*)d_out;

    // ws layout: [cnt 32 KB][zrow 512 B][bkt 6 MB]
    int* cntg = (int*)d_ws;
    const size_t cnt_bytes  = (size_t)NNODES * sizeof(int);          // 32 KB
    const float4* zrow = (const float4*)((char*)d_ws + cnt_bytes);   // 512 B
    int* bkt = (int*)((char*)d_ws + cnt_bytes + 512);
    const int E = in_sizes[1] / 2;

    // Re-poisoned every launch: zero counters + zero-row (33 KB only).
    hipMemsetAsync(d_ws, 0, cnt_bytes + 512, stream);

    bucket_scatter<<<dim3((E + 255) / 256), dim3(256), 0, stream>>>(
        ei, E, cntg, bkt, (const float4*)x);
    gcn_fused<<<dim3(NNODES / M), dim3(NTHR), 0, stream>>>(
        x, ei, E, cntg, bkt, zrow, W, b, out);
}

// Round 4
// 100.359 us; speedup vs baseline: 1.0640x; 1.0258x over previous
//
#include <hip/hip_runtime.h>

// SimpleGCNConv: out = rownorm(setadj(edge_index) + I) @ x @ W^T + b
// N=8192, E=262144, D=128, fp32. Dedup via dense bitmap (8 MB in d_ws);
// duplicate edges count ONCE (.set), self-loop added ON TOP.
//
// R8 = R4 revert (best measured: 100.4 us) + int4 edge loads in scatter.
// R5 (M=8, per-wave-pair bounds) and R7 (buckets + LDS dedup) both measured
// slower; the window is dominated by the harness's 256 MiB workspace poison
// fills (~81 us of ~100), so structure reverts to the proven best.

typedef unsigned int uint32;

#define NNODES 8192
#define DF 128
#define WPR 256        // bitmap words per row
#define M 4            // nodes per block
#define CAP 192        // neighbor list cap (deg ~ Poisson(32); max row ~70)

__global__ void edge_scatter(const int* __restrict__ ei, int E,
                             uint32* __restrict__ bm) {
    int e4 = blockIdx.x * blockDim.x + threadIdx.x;
    int E4 = E >> 2;
    if (e4 < E4) {
        const int4* s4 = (const int4*)ei;
        const int4* d4 = (const int4*)(ei + E);
        int4 s = s4[e4], d = d4[e4];
        atomicOr(&bm[(size_t)s.x * WPR + (d.x >> 5)], 1u << (d.x & 31));
        atomicOr(&bm[(size_t)s.y * WPR + (d.y >> 5)], 1u << (d.y & 31));
        atomicOr(&bm[(size_t)s.z * WPR + (d.z >> 5)], 1u << (d.z & 31));
        atomicOr(&bm[(size_t)s.w * WPR + (d.w >> 5)], 1u << (d.w & 31));
    }
    if (e4 == 0) {                        // tail (E%4 != 0) — none for E=262144
        for (int e = E & ~3; e < E; ++e) {
            int src = ei[e], dst = ei[E + e];
            atomicOr(&bm[(size_t)src * WPR + (dst >> 5)], 1u << (dst & 31));
        }
    }
}

__global__ __launch_bounds__(128) void gcn_fused(
    const float* __restrict__ x,
    const uint32* __restrict__ bm,
    const float4* __restrict__ zrow,   // 128 zero floats (in d_ws, memset)
    const float* __restrict__ W,
    const float* __restrict__ b,
    float* __restrict__ out)
{
    __shared__ int nbr[M][CAP];
    __shared__ int cnt_s[M];
    __shared__ __align__(16) float part[M][4][DF];  // per-group partials (8 KB)
    __shared__ float agg[M][DF];

    const int t    = threadIdx.x;
    const int lane = t & 63;
    const int wv   = t >> 6;          // 0/1
    const int node0 = blockIdx.x * M;

    // ---- Phase A: one wave per bitmap row; prefix-sum offsets, no atomics.
    #pragma unroll
    for (int pass = 0; pass < 2; ++pass) {
        const int m = pass * 2 + wv;
        const uint4* r = (const uint4*)(bm + (size_t)(node0 + m) * WPR);
        uint4 w = r[lane];                           // 16 B/lane, coalesced
        int c = __popc(w.x) + __popc(w.y) + __popc(w.z) + __popc(w.w);
        int v = c;                                   // inclusive wave scan
        #pragma unroll
        for (int d = 1; d < 64; d <<= 1) {
            int up = __shfl_up(v, d);
            if (lane >= d) v += up;
        }
        int off = v - c;                             // exclusive prefix
        if (lane == 63) cnt_s[m] = v;
        uint32 ws[4] = {w.x, w.y, w.z, w.w};
        #pragma unroll
        for (int q = 0; q < 4; ++q) {
            uint32 word = ws[q];
            int base = (4 * lane + q) << 5;
            while (word) {
                int bit = __ffs(word) - 1; word &= word - 1;
                if (off < CAP) nbr[m][off] = base + bit;
                off++;
            }
        }
    }
    __syncthreads();

    const int c0 = cnt_s[0], c1 = cnt_s[1], c2 = cnt_s[2], c3 = cnt_s[3];
    int Lmax = max(max(c0, c1), max(c2, c3));
    const bool overflow = (Lmax > CAP);              // statistically never
    int L = (min(Lmax, CAP) + 3) & ~3;               // pad to multiple of 4

    // Pad lists with -1 (sentinel -> zero row).
    for (int m = 0; m < M; ++m) {
        int cm = min(cnt_s[m], CAP);
        for (int k = cm + t; k < L; k += 128) nbr[m][k] = -1;
    }
    __syncthreads();

    if (!overflow) {
        // ---- Phase B: float4 gather. group g handles neighbors k===g (mod 4);
        // all M chains interleaved per iteration -> 4 loads in flight/thread.
        const int g = t >> 5;       // 0..3
        const int c = t & 31;       // float4 chunk
        const float4* x4 = (const float4*)x;

        float4 acc[M];
        #pragma unroll
        for (int m = 0; m < M; ++m) acc[m] = make_float4(0.f, 0.f, 0.f, 0.f);

        for (int k = g; k < L; k += 4) {
            #pragma unroll
            for (int m = 0; m < M; ++m) {
                int j = nbr[m][k];
                const float4* p = (j >= 0) ? (x4 + (size_t)j * (DF / 4) + c)
                                           : (zrow + c);
                float4 vx = *p;
                acc[m].x += vx.x; acc[m].y += vx.y;
                acc[m].z += vx.z; acc[m].w += vx.w;
            }
        }

        #pragma unroll
        for (int m = 0; m < M; ++m)
            *(float4*)&part[m][g][c * 4] = acc[m];
        __syncthreads();

        // Reduce groups, add eye, normalize.
        #pragma unroll
        for (int m = 0; m < M; ++m) {
            float s = part[m][0][t] + part[m][1][t]
                    + part[m][2][t] + part[m][3][t];
            s += x[(size_t)(node0 + m) * DF + t];    // self-loop on top
            agg[m][t] = s / (float)(1 + cnt_s[m]);
        }
    } else {
        // Fallback (correctness-safe, never expected): uniform bitmap rescan.
        for (int m = 0; m < M; ++m) {
            const uint32* r = bm + (size_t)(node0 + m) * WPR;
            float acc = x[(size_t)(node0 + m) * DF + t];
            for (int w = 0; w < WPR; ++w) {
                uint32 word = r[w];
                int base = w << 5;
                while (word) {
                    int bit = __ffs(word) - 1; word &= word - 1;
                    acc += x[(size_t)(base + bit) * DF + t];
                }
            }
            agg[m][t] = acc / (float)(1 + cnt_s[m]);
        }
    }
    __syncthreads();

    // ---- Phase C: fused linear. Thread t owns out dim t for all M nodes.
    const float4* Wrow = (const float4*)(W + (size_t)t * DF);
    float bias = b[t];
    float sum[M];
    #pragma unroll
    for (int m = 0; m < M; ++m) sum[m] = bias;

    #pragma unroll 8
    for (int c4 = 0; c4 < DF / 4; ++c4) {
        float4 wvv = Wrow[c4];
        #pragma unroll
        for (int m = 0; m < M; ++m) {
            sum[m] += wvv.x * agg[m][c4 * 4 + 0] + wvv.y * agg[m][c4 * 4 + 1]
                    + wvv.z * agg[m][c4 * 4 + 2] + wvv.w * agg[m][c4 * 4 + 3];
        }
    }
    #pragma unroll
    for (int m = 0; m < M; ++m)
        out[(size_t)(node0 + m) * DF + t] = sum[m];
}

extern "C" void kernel_launch(void* const* d_in, const int* in_sizes, int n_in,
                              void* d_out, int out_size, void* d_ws, size_t ws_size,
                              hipStream_t stream) {
    const float* x = (const float*)d_in[0];
    const int*  ei = (const int*)d_in[1];
    const float* W = (const float*)d_in[2];
    const float* b = (const float*)d_in[3];
    float* out = (float*)d_out;

    uint32* bm = (uint32*)d_ws;
    const size_t bm_bytes = (size_t)NNODES * WPR * sizeof(uint32);   // 8 MB
    const float4* zrow = (const float4*)((char*)d_ws + bm_bytes);    // 512 B zeros
    const int E = in_sizes[1] / 2;

    // d_ws is re-poisoned before every launch: zero bitmap + zero-row.
    hipMemsetAsync(d_ws, 0, bm_bytes + DF * sizeof(float), stream);

    int E4 = E >> 2;
    edge_scatter<<<dim3((E4 + 255) / 256), dim3(256), 0, stream>>>(ei, E, bm);
    gcn_fused<<<dim3(NNODES / M), dim3(128), 0, stream>>>(x, bm, zrow, W, b, out);
}

// Round 5
// 100.206 us; speedup vs baseline: 1.0656x; 1.0015x over previous
//
#include <hip/hip_runtime.h>

// SimpleGCNConv: out = rownorm(setadj(edge_index) + I) @ x @ W^T + b
// N=8192, E=262144, D=128, fp32. Dedup via dense bitmap (8 MB in d_ws);
// duplicate edges count ONCE (.set), self-loop added ON TOP.
//
// R9 = R8 (best: 100.36 us) + gather-latency attack:
//  - zero_and_warm kernel replaces hipMemsetAsync: zeros bitmap AND streams
//    x into L3/L2 (the harness's 256 MiB poison fill exactly evicts L3 every
//    iteration, so Phase B otherwise first-touches x from HBM at ~900 cy).
//  - Phase B k-loop unrolled x2 -> 8 gather loads in flight per thread.

typedef unsigned int uint32;

#define NNODES 8192
#define DF 128
#define WPR 256        // bitmap words per row
#define M 4            // nodes per block
#define CAP 192        // neighbor list cap (deg ~ Poisson(32); max row ~70)
#define NZ4 ((NNODES * WPR) / 4 + 32)   // uint4s: bitmap (524288) + zrow (32)

__global__ __launch_bounds__(256) void zero_and_warm(
    uint32* __restrict__ bm, const float4* __restrict__ x4) {
    const int gtid = blockIdx.x * 256 + threadIdx.x;   // 262144 threads
    uint4* z4 = (uint4*)bm;
    const uint4 zz = make_uint4(0u, 0u, 0u, 0u);
    // Zero 8 MB bitmap + 512 B zrow (2 uint4 per thread + tail).
    z4[gtid] = zz;
    z4[gtid + 262144] = zz;
    if (gtid < NZ4 - 524288) z4[gtid + 524288] = zz;
    // Warm all of x (4 MB = 262144 float4) into L3/L2.
    float4 px = x4[gtid];
    asm volatile("" :: "v"(px.x), "v"(px.y), "v"(px.z), "v"(px.w));
}

__global__ void edge_scatter(const int* __restrict__ ei, int E,
                             uint32* __restrict__ bm) {
    int e4 = blockIdx.x * blockDim.x + threadIdx.x;
    int E4 = E >> 2;
    if (e4 < E4) {
        const int4* s4 = (const int4*)ei;
        const int4* d4 = (const int4*)(ei + E);
        int4 s = s4[e4], d = d4[e4];
        atomicOr(&bm[(size_t)s.x * WPR + (d.x >> 5)], 1u << (d.x & 31));
        atomicOr(&bm[(size_t)s.y * WPR + (d.y >> 5)], 1u << (d.y & 31));
        atomicOr(&bm[(size_t)s.z * WPR + (d.z >> 5)], 1u << (d.z & 31));
        atomicOr(&bm[(size_t)s.w * WPR + (d.w >> 5)], 1u << (d.w & 31));
    }
    if (e4 == 0) {                        // tail (E%4 != 0) — none for E=262144
        for (int e = E & ~3; e < E; ++e) {
            int src = ei[e], dst = ei[E + e];
            atomicOr(&bm[(size_t)src * WPR + (dst >> 5)], 1u << (dst & 31));
        }
    }
}

__global__ __launch_bounds__(128) void gcn_fused(
    const float* __restrict__ x,
    const uint32* __restrict__ bm,
    const float4* __restrict__ zrow,   // 128 zero floats (in d_ws, zeroed)
    const float* __restrict__ W,
    const float* __restrict__ b,
    float* __restrict__ out)
{
    __shared__ int nbr[M][CAP];
    __shared__ int cnt_s[M];
    __shared__ __align__(16) float part[M][4][DF];  // per-group partials (8 KB)
    __shared__ float agg[M][DF];

    const int t    = threadIdx.x;
    const int lane = t & 63;
    const int wv   = t >> 6;          // 0/1
    const int node0 = blockIdx.x * M;

    // ---- Phase A: one wave per bitmap row; prefix-sum offsets, no atomics.
    #pragma unroll
    for (int pass = 0; pass < 2; ++pass) {
        const int m = pass * 2 + wv;
        const uint4* r = (const uint4*)(bm + (size_t)(node0 + m) * WPR);
        uint4 w = r[lane];                           // 16 B/lane, coalesced
        int c = __popc(w.x) + __popc(w.y) + __popc(w.z) + __popc(w.w);
        int v = c;                                   // inclusive wave scan
        #pragma unroll
        for (int d = 1; d < 64; d <<= 1) {
            int up = __shfl_up(v, d);
            if (lane >= d) v += up;
        }
        int off = v - c;                             // exclusive prefix
        if (lane == 63) cnt_s[m] = v;
        uint32 ws[4] = {w.x, w.y, w.z, w.w};
        #pragma unroll
        for (int q = 0; q < 4; ++q) {
            uint32 word = ws[q];
            int base = (4 * lane + q) << 5;
            while (word) {
                int bit = __ffs(word) - 1; word &= word - 1;
                if (off < CAP) nbr[m][off] = base + bit;
                off++;
            }
        }
    }
    __syncthreads();

    const int c0 = cnt_s[0], c1 = cnt_s[1], c2 = cnt_s[2], c3 = cnt_s[3];
    int Lmax = max(max(c0, c1), max(c2, c3));
    const bool overflow = (Lmax > CAP);              // statistically never
    int L = (min(Lmax, CAP) + 7) & ~7;               // pad to multiple of 8

    // Pad lists with -1 (sentinel -> zero row). L <= CAP (192 = 8*24).
    for (int m = 0; m < M; ++m) {
        int cm = min(cnt_s[m], CAP);
        for (int k = cm + t; k < L; k += 128) nbr[m][k] = -1;
    }
    __syncthreads();

    if (!overflow) {
        // ---- Phase B: float4 gather. group g handles k===g (mod 4); k-loop
        // unrolled x2 and all M chains interleaved -> 8 loads in flight.
        const int g = t >> 5;       // 0..3
        const int c = t & 31;       // float4 chunk
        const float4* x4 = (const float4*)x;

        float4 acc[M];
        #pragma unroll
        for (int m = 0; m < M; ++m) acc[m] = make_float4(0.f, 0.f, 0.f, 0.f);

        for (int k = g; k < L; k += 8) {
            const float4* p[2][M];
            #pragma unroll
            for (int m = 0; m < M; ++m) {
                int j0 = nbr[m][k];
                int j1 = nbr[m][k + 4];
                p[0][m] = (j0 >= 0) ? (x4 + (size_t)j0 * (DF / 4) + c) : (zrow + c);
                p[1][m] = (j1 >= 0) ? (x4 + (size_t)j1 * (DF / 4) + c) : (zrow + c);
            }
            float4 v0[M], v1[M];
            #pragma unroll
            for (int m = 0; m < M; ++m) v0[m] = *p[0][m];
            #pragma unroll
            for (int m = 0; m < M; ++m) v1[m] = *p[1][m];
            #pragma unroll
            for (int m = 0; m < M; ++m) {
                acc[m].x += v0[m].x + v1[m].x;
                acc[m].y += v0[m].y + v1[m].y;
                acc[m].z += v0[m].z + v1[m].z;
                acc[m].w += v0[m].w + v1[m].w;
            }
        }

        #pragma unroll
        for (int m = 0; m < M; ++m)
            *(float4*)&part[m][g][c * 4] = acc[m];
        __syncthreads();

        // Reduce groups, add eye, normalize.
        #pragma unroll
        for (int m = 0; m < M; ++m) {
            float s = part[m][0][t] + part[m][1][t]
                    + part[m][2][t] + part[m][3][t];
            s += x[(size_t)(node0 + m) * DF + t];    // self-loop on top
            agg[m][t] = s / (float)(1 + cnt_s[m]);
        }
    } else {
        // Fallback (correctness-safe, never expected): uniform bitmap rescan.
        for (int m = 0; m < M; ++m) {
            const uint32* r = bm + (size_t)(node0 + m) * WPR;
            float acc = x[(size_t)(node0 + m) * DF + t];
            for (int w = 0; w < WPR; ++w) {
                uint32 word = r[w];
                int base = w << 5;
                while (word) {
                    int bit = __ffs(word) - 1; word &= word - 1;
                    acc += x[(size_t)(base + bit) * DF + t];
                }
            }
            agg[m][t] = acc / (float)(1 + cnt_s[m]);
        }
    }
    __syncthreads();

    // ---- Phase C: fused linear. Thread t owns out dim t for all M nodes.
    const float4* Wrow = (const float4*)(W + (size_t)t * DF);
    float bias = b[t];
    float sum[M];
    #pragma unroll
    for (int m = 0; m < M; ++m) sum[m] = bias;

    #pragma unroll 8
    for (int c4 = 0; c4 < DF / 4; ++c4) {
        float4 wvv = Wrow[c4];
        #pragma unroll
        for (int m = 0; m < M; ++m) {
            sum[m] += wvv.x * agg[m][c4 * 4 + 0] + wvv.y * agg[m][c4 * 4 + 1]
                    + wvv.z * agg[m][c4 * 4 + 2] + wvv.w * agg[m][c4 * 4 + 3];
        }
    }
    #pragma unroll
    for (int m = 0; m < M; ++m)
        out[(size_t)(node0 + m) * DF + t] = sum[m];
}

extern "C" void kernel_launch(void* const* d_in, const int* in_sizes, int n_in,
                              void* d_out, int out_size, void* d_ws, size_t ws_size,
                              hipStream_t stream) {
    const float* x = (const float*)d_in[0];
    const int*  ei = (const int*)d_in[1];
    const float* W = (const float*)d_in[2];
    const float* b = (const float*)d_in[3];
    float* out = (float*)d_out;

    uint32* bm = (uint32*)d_ws;
    const size_t bm_bytes = (size_t)NNODES * WPR * sizeof(uint32);   // 8 MB
    const float4* zrow = (const float4*)((char*)d_ws + bm_bytes);    // 512 B zeros
    const int E = in_sizes[1] / 2;

    // Zero bitmap + zrow AND warm x into L3/L2 (poison fill evicted it).
    zero_and_warm<<<dim3(1024), dim3(256), 0, stream>>>(bm, (const float4*)x);

    int E4 = E >> 2;
    edge_scatter<<<dim3((E4 + 255) / 256), dim3(256), 0, stream>>>(ei, E, bm);
    gcn_fused<<<dim3(NNODES / M), dim3(128), 0, stream>>>(x, bm, zrow, W, b, out);
}